// Round 1
// baseline (173.372 us; speedup 1.0000x reference)
//
#include <hip/hip_runtime.h>
#include <stdint.h>

typedef __bf16 bf16;
typedef __bf16 bf16x8 __attribute__((ext_vector_type(8)));
typedef float f32x4 __attribute__((ext_vector_type(4)));

#define MFMA16(a, b, c) __builtin_amdgcn_mfma_f32_16x16x32_bf16((a), (b), (c), 0, 0, 0)

// async global->LDS DMA, 16B per lane. LDS dest must be wave-uniform; HW writes base + lane*16.
__device__ __forceinline__ void ldsdma16(const void* g, void* l) {
  __builtin_amdgcn_global_load_lds((const __attribute__((address_space(1))) void*)g,
                                   (__attribute__((address_space(3))) void*)l, 16, 0, 0);
}

// ---------------------------------------------------------------------------
// prep: cast x (fp32 [4096,1024]) -> bf16
// ---------------------------------------------------------------------------
__global__ __launch_bounds__(256) void prep_cast(const float* __restrict__ x,
                                                 bf16* __restrict__ xb) {
  int idx = (blockIdx.x * 256 + threadIdx.x) * 4;
  float4 v = *(const float4*)(x + idx);
  union { bf16 h[4]; uint2 u; } p;
  p.h[0] = (bf16)v.x; p.h[1] = (bf16)v.y; p.h[2] = (bf16)v.z; p.h[3] = (bf16)v.w;
  *(uint2*)(xb + idx) = p.u;
}

// ---------------------------------------------------------------------------
// prep: transpose-cast W [k][n] fp32 -> WT [n][k] bf16 (4 matrices via blockIdx.z)
// LDS 64x65 tile: both global read and write coalesced, LDS conflict-free.
// ---------------------------------------------------------------------------
__global__ __launch_bounds__(256) void prep_transpose(const float* __restrict__ Wq,
                                                      const float* __restrict__ Wk,
                                                      const float* __restrict__ Wv,
                                                      const float* __restrict__ Wo,
                                                      bf16* __restrict__ WT) {
  __shared__ float tile[64][65];
  const float* src = blockIdx.z == 0 ? Wq : blockIdx.z == 1 ? Wk : blockIdx.z == 2 ? Wv : Wo;
  bf16* dst = WT + (size_t)blockIdx.z * 1024 * 1024;
  const int k0 = blockIdx.y * 64, n0 = blockIdx.x * 64;
  const int rr = threadIdx.x >> 6, c = threadIdx.x & 63;
#pragma unroll
  for (int i = 0; i < 16; ++i) {
    int r = i * 4 + rr;
    tile[r][c] = src[(size_t)(k0 + r) * 1024 + n0 + c];
  }
  __syncthreads();
#pragma unroll
  for (int i = 0; i < 16; ++i) {
    int r = i * 4 + rr;
    dst[(size_t)(n0 + r) * 1024 + k0 + c] = (bf16)tile[c][r];
  }
}

// ---------------------------------------------------------------------------
// Shared 128x128 GEMM mainloop (m97 structure): C = A[M,K] * BT[N,K]^T
// BK=32, 4 waves in 2x2, each wave 64x64 (4x4 mfma_16x16x32 tiles).
// LDS tiles stored as 16B chunks with XOR swizzle (c ^ ((row>>1)&3)) so
// ds_read_b128 fragment reads are 2-way-conflict (free, m136) while the
// global_load_lds destination stays pad-free (wave-uniform base + lane*16).
// ---------------------------------------------------------------------------
__device__ __forceinline__ void gemm_mainloop(const bf16* __restrict__ A,
                                              const bf16* __restrict__ BT, int K,
                                              int m0, int n0, bf16* As, bf16* Bs,
                                              f32x4 acc[4][4]) {
  const int tid = threadIdx.x;
  const int lane = tid & 63;
  const int wave = tid >> 6;
  const int wm = wave >> 1, wn = wave & 1;
  const int quad = lane >> 4, l16 = lane & 15;

  const f32x4 zero = {0.f, 0.f, 0.f, 0.f};
#pragma unroll
  for (int i = 0; i < 4; ++i)
#pragma unroll
    for (int j = 0; j < 4; ++j) acc[i][j] = zero;

  const int ch0 = wave * 128 + lane;

  for (int k0 = 0; k0 < K; k0 += 32) {
#pragma unroll
    for (int c = 0; c < 2; ++c) {
      int chunk = ch0 + c * 64;           // 0..511 16B chunks
      int row = chunk >> 2;               // tile row 0..127
      int cg = (chunk & 3) ^ ((row >> 1) & 3);  // swizzled source chunk
      ldsdma16(A + (size_t)(m0 + row) * K + k0 + cg * 8,
               (char*)As + (size_t)(wave * 128 + c * 64) * 16);
      ldsdma16(BT + (size_t)(n0 + row) * K + k0 + cg * 8,
               (char*)Bs + (size_t)(wave * 128 + c * 64) * 16);
    }
    __syncthreads();
    bf16x8 af[4], bfv[4];
#pragma unroll
    for (int i = 0; i < 4; ++i) {
      int ra = wm * 64 + i * 16 + l16;
      af[i] = ((const bf16x8*)As)[ra * 4 + (quad ^ ((ra >> 1) & 3))];
      int rb = wn * 64 + i * 16 + l16;
      bfv[i] = ((const bf16x8*)Bs)[rb * 4 + (quad ^ ((rb >> 1) & 3))];
    }
#pragma unroll
    for (int i = 0; i < 4; ++i)
#pragma unroll
      for (int j = 0; j < 4; ++j) acc[i][j] = MFMA16(af[i], bfv[j], acc[i][j]);
    __syncthreads();
  }
}

// ---------------------------------------------------------------------------
// QKV GEMM: xb[4096,1024] @ Wqkv -> Q/K/V in [B,H,S,HD] bf16. Q gets *SCALE.
// ---------------------------------------------------------------------------
__global__ __launch_bounds__(256) void qkv_gemm(const bf16* __restrict__ xb,
                                                const bf16* __restrict__ WT,
                                                const float* __restrict__ bq,
                                                const float* __restrict__ bk,
                                                const float* __restrict__ bv,
                                                bf16* __restrict__ Qd,
                                                bf16* __restrict__ Kd,
                                                bf16* __restrict__ Vd) {
  __shared__ bf16 As[128 * 32] __attribute__((aligned(16)));
  __shared__ bf16 Bs[128 * 32] __attribute__((aligned(16)));
  f32x4 acc[4][4];
  const int m0 = blockIdx.y * 128, n0 = blockIdx.x * 128;
  gemm_mainloop(xb, WT, 1024, m0, n0, As, Bs, acc);

  const int lane = threadIdx.x & 63, wave = threadIdx.x >> 6;
  const int wm = wave >> 1, wn = wave & 1;
  const int quad = lane >> 4, l16 = lane & 15;
#pragma unroll
  for (int j = 0; j < 4; ++j) {
    const int n = n0 + wn * 64 + j * 16 + l16;  // 0..3071
    const int sel = n >> 10, d = n & 1023;
    const float bias = (sel == 0 ? bq : sel == 1 ? bk : bv)[d];
    bf16* dst = (sel == 0 ? Qd : sel == 1 ? Kd : Vd);
    const float scl = (sel == 0) ? 0.125f : 1.f;  // fold softmax scale into Q (2^-3, exact)
    const int h = d >> 6, hd = d & 63;
#pragma unroll
    for (int i = 0; i < 4; ++i) {
#pragma unroll
      for (int r = 0; r < 4; ++r) {
        const int token = m0 + wm * 64 + i * 16 + quad * 4 + r;
        const int bb = token >> 11, s = token & 2047;
        const float v = (acc[i][j][r] + bias) * scl;
        dst[((((size_t)bb * 16 + h) * 2048 + s) << 6) + hd] = (bf16)v;
      }
    }
  }
}

// ---------------------------------------------------------------------------
// Sliding-window attention. 1 block = (b, h, 64-query tile), 4 waves, each
// wave owns 16 query rows. Key chunks of 64, <=5 per tile. Online softmax,
// mask value finite -1e30 (all-masked chunks produce garbage that alpha=0
// wipes once a real key arrives; every row eventually has j=i valid).
// ---------------------------------------------------------------------------
__global__ __launch_bounds__(256) void attn_kernel(const bf16* __restrict__ Q,
                                                   const bf16* __restrict__ K,
                                                   const bf16* __restrict__ V,
                                                   bf16* __restrict__ Ao) {
  __shared__ bf16 Qs[64 * 64] __attribute__((aligned(16)));   // swizzled chunks
  __shared__ bf16 Ks[64 * 64] __attribute__((aligned(16)));   // swizzled chunks
  __shared__ bf16 Vt[64 * 72] __attribute__((aligned(16)));   // [hd][key], pad 8
  __shared__ bf16 Ps[4][16 * 72] __attribute__((aligned(16))); // per-wave P scratch

  const int tid = threadIdx.x, lane = tid & 63, wave = tid >> 6;
  const int quad = lane >> 4, l16 = lane & 15;
  const int qt = blockIdx.x, h = blockIdx.y, b = blockIdx.z;
  const int q0 = qt * 64;
  const size_t base = ((size_t)(b * 16 + h)) * 2048 * 64;
  const bf16* Qb = Q + base + (size_t)q0 * 64;
  const bf16* Kb = K + base;
  const bf16* Vb = V + base;

  // stage Q tile (512 chunks, swizzle c ^ (row&7) over 8-chunk rows)
#pragma unroll
  for (int c = 0; c < 2; ++c) {
    int chunk = wave * 128 + c * 64 + lane;
    int row = chunk >> 3;
    int cg = (chunk & 7) ^ (row & 7);
    ldsdma16(Qb + (size_t)row * 64 + cg * 8, (char*)Qs + (size_t)(wave * 128 + c * 64) * 16);
  }
  __syncthreads();

  bf16x8 qa[2];
  {
    int row = wave * 16 + l16;
    qa[0] = ((const bf16x8*)Qs)[row * 8 + ((0 * 4 + quad) ^ (row & 7))];
    qa[1] = ((const bf16x8*)Qs)[row * 8 + ((1 * 4 + quad) ^ (row & 7))];
  }

  float mrow[4], lrow[4];
  f32x4 oacc[4];
  const f32x4 zero = {0.f, 0.f, 0.f, 0.f};
#pragma unroll
  for (int r = 0; r < 4; ++r) { mrow[r] = -1e30f; lrow[r] = 0.f; }
#pragma unroll
  for (int t = 0; t < 4; ++t) oacc[t] = zero;

  const int clo = (qt >= 4) ? (qt - 4) : 0;
  for (int ck = clo; ck <= qt; ++ck) {
    const int c0 = ck * 64;
    __syncthreads();  // previous chunk's Ks/Vt use done
    // stage K chunk via DMA
#pragma unroll
    for (int c = 0; c < 2; ++c) {
      int chunk = wave * 128 + c * 64 + lane;
      int row = chunk >> 3;
      int cg = (chunk & 7) ^ (row & 7);
      ldsdma16(Kb + (size_t)(c0 + row) * 64 + cg * 8,
               (char*)Ks + (size_t)(wave * 128 + c * 64) * 16);
    }
    // stage V chunk transposed: Vt[hd][key]
    {
      int key = tid >> 2, hc = (tid & 3) * 16;
      const bf16* vp = Vb + (size_t)(c0 + key) * 64 + hc;
      bf16x8 v0 = *(const bf16x8*)vp;
      bf16x8 v1 = *(const bf16x8*)(vp + 8);
#pragma unroll
      for (int i = 0; i < 8; ++i) Vt[(hc + i) * 72 + key] = v0[i];
#pragma unroll
      for (int i = 0; i < 8; ++i) Vt[(hc + 8 + i) * 72 + key] = v1[i];
    }
    __syncthreads();

    // scores S = Q K^T (scale already folded into Q)
    f32x4 sc[4];
#pragma unroll
    for (int nt = 0; nt < 4; ++nt) {
      int key = nt * 16 + l16;
      bf16x8 kb0 = ((const bf16x8*)Ks)[key * 8 + ((0 * 4 + quad) ^ (key & 7))];
      bf16x8 kb1 = ((const bf16x8*)Ks)[key * 8 + ((1 * 4 + quad) ^ (key & 7))];
      f32x4 s = zero;
      s = MFMA16(qa[0], kb0, s);
      s = MFMA16(qa[1], kb1, s);
      sc[nt] = s;
    }

    // mask + online softmax
    float alpha[4];
#pragma unroll
    for (int r = 0; r < 4; ++r) {
      const int i = q0 + wave * 16 + quad * 4 + r;
      float mx = -1e30f;
#pragma unroll
      for (int nt = 0; nt < 4; ++nt) {
        const int j = c0 + nt * 16 + l16;
        const bool valid = (j <= i) && (j + 255 >= i);
        const float s = valid ? sc[nt][r] : -1e30f;
        sc[nt][r] = s;
        mx = fmaxf(mx, s);
      }
#pragma unroll
      for (int m = 8; m >= 1; m >>= 1) mx = fmaxf(mx, __shfl_xor(mx, m, 64));
      const float mnew = fmaxf(mrow[r], mx);
      alpha[r] = __expf(mrow[r] - mnew);
      mrow[r] = mnew;
      float rs = 0.f;
#pragma unroll
      for (int nt = 0; nt < 4; ++nt) {
        const float p = __expf(sc[nt][r] - mnew);
        sc[nt][r] = p;
        rs += p;
      }
#pragma unroll
      for (int m = 8; m >= 1; m >>= 1) rs += __shfl_xor(rs, m, 64);
      lrow[r] = lrow[r] * alpha[r] + rs;
    }

    // P: C-layout -> A-layout via per-wave LDS round-trip (bf16)
#pragma unroll
    for (int nt = 0; nt < 4; ++nt)
#pragma unroll
      for (int r = 0; r < 4; ++r)
        Ps[wave][(quad * 4 + r) * 72 + nt * 16 + l16] = (bf16)sc[nt][r];
    asm volatile("s_waitcnt lgkmcnt(0)" ::: "memory");  // same-wave LDS RAW
    bf16x8 pa0 = ((const bf16x8*)Ps[wave])[l16 * 9 + quad];
    bf16x8 pa1 = ((const bf16x8*)Ps[wave])[l16 * 9 + 4 + quad];

    // O = O*alpha + P V
#pragma unroll
    for (int ht = 0; ht < 4; ++ht) {
      f32x4 o = oacc[ht];
#pragma unroll
      for (int r = 0; r < 4; ++r) o[r] *= alpha[r];
      const int n = ht * 16 + l16;
      bf16x8 vb0 = ((const bf16x8*)Vt)[n * 9 + quad];
      bf16x8 vb1 = ((const bf16x8*)Vt)[n * 9 + 4 + quad];
      o = MFMA16(pa0, vb0, o);
      o = MFMA16(pa1, vb1, o);
      oacc[ht] = o;
    }
  }

  // epilogue: normalize, write [B,S,H*HD] bf16
#pragma unroll
  for (int r = 0; r < 4; ++r) {
    const float inv = 1.f / lrow[r];
    const int row = q0 + wave * 16 + quad * 4 + r;
    const size_t outb = ((size_t)(b * 2048 + row)) * 1024 + h * 64;
#pragma unroll
    for (int ht = 0; ht < 4; ++ht)
      Ao[outb + ht * 16 + l16] = (bf16)(oacc[ht][r] * inv);
  }
}

// ---------------------------------------------------------------------------
// Output GEMM: Ao[4096,1024] @ Wo + bo -> fp32 out
// ---------------------------------------------------------------------------
__global__ __launch_bounds__(256) void out_gemm(const bf16* __restrict__ Ain,
                                                const bf16* __restrict__ WoT,
                                                const float* __restrict__ bo,
                                                float* __restrict__ out) {
  __shared__ bf16 As[128 * 32] __attribute__((aligned(16)));
  __shared__ bf16 Bs[128 * 32] __attribute__((aligned(16)));
  f32x4 acc[4][4];
  const int m0 = blockIdx.y * 128, n0 = blockIdx.x * 128;
  gemm_mainloop(Ain, WoT, 1024, m0, n0, As, Bs, acc);

  const int lane = threadIdx.x & 63, wave = threadIdx.x >> 6;
  const int wm = wave >> 1, wn = wave & 1;
  const int quad = lane >> 4, l16 = lane & 15;
#pragma unroll
  for (int j = 0; j < 4; ++j) {
    const int n = n0 + wn * 64 + j * 16 + l16;
    const float bias = bo[n];
#pragma unroll
    for (int i = 0; i < 4; ++i) {
#pragma unroll
      for (int r = 0; r < 4; ++r) {
        const int token = m0 + wm * 64 + i * 16 + quad * 4 + r;
        out[(size_t)token * 1024 + n] = acc[i][j][r] + bias;
      }
    }
  }
}

// ---------------------------------------------------------------------------
extern "C" void kernel_launch(void* const* d_in, const int* in_sizes, int n_in,
                              void* d_out, int out_size, void* d_ws, size_t ws_size,
                              hipStream_t stream) {
  const float* x  = (const float*)d_in[0];
  const float* Wq = (const float*)d_in[1];
  const float* bq = (const float*)d_in[2];
  const float* Wk = (const float*)d_in[3];
  const float* bk = (const float*)d_in[4];
  const float* Wv = (const float*)d_in[5];
  const float* bv = (const float*)d_in[6];
  const float* Wo = (const float*)d_in[7];
  const float* bo = (const float*)d_in[8];
  float* out = (float*)d_out;

  char* ws = (char*)d_ws;
  bf16* xb = (bf16*)(ws);                      //  8 MB  x bf16
  bf16* WT = (bf16*)(ws + ((size_t)8 << 20));  //  8 MB  WqT|WkT|WvT|WoT bf16 [n][k]
  bf16* Qd = (bf16*)(ws + ((size_t)16 << 20)); //  8 MB  [B,H,S,HD]
  bf16* Kd = (bf16*)(ws + ((size_t)24 << 20)); //  8 MB
  bf16* Vd = (bf16*)(ws + ((size_t)32 << 20)); //  8 MB
  bf16* Ao = (bf16*)(ws + ((size_t)40 << 20)); //  8 MB  [B,S,DIM]

  prep_cast<<<4096, 256, 0, stream>>>(x, xb);
  prep_transpose<<<dim3(16, 16, 4), 256, 0, stream>>>(Wq, Wk, Wv, Wo, WT);
  qkv_gemm<<<dim3(24, 32), 256, 0, stream>>>(xb, WT, bq, bk, bv, Qd, Kd, Vd);
  attn_kernel<<<dim3(32, 16, 2), 256, 0, stream>>>(Qd, Kd, Vd, Ao);
  out_gemm<<<dim3(8, 32), 256, 0, stream>>>(Ao, WT + (size_t)3 * 1024 * 1024, bo, out);
}